// Round 2
// baseline (1388.001 us; speedup 1.0000x reference)
//
#include <hip/hip_runtime.h>

// Problem constants (B=2, T=64 -> N=128 images; C=O=16; H=W=128; nh=8, hc=2, D=32768)
#define NIMG 128
#define CH   16
#define HPIX 128
#define WPIX 128
#define HW   16384          // 128*128
#define NHEAD 8
#define TT   64             // tokens
#define DHEAD 32768         // 2*HW
#define QSZ  33554432       // NIMG*CH*HW floats per q/k/v buffer
#define NSLICE 32
#define SCALE_ATT 0.0055242717280199f  // 1/sqrt(32768)

// conv spatial tile
#define TH 4
#define TW 64

// ---------------- conv 3x3 (pad 1), NC=3 for fused QKV, NC=1 for output conv ----------
template<int NC>
__global__ __launch_bounds__(256) void conv3x3_k(
    const float* __restrict__ xin,
    const float* __restrict__ w0c, const float* __restrict__ b0c,
    const float* __restrict__ w1c, const float* __restrict__ b1c,
    const float* __restrict__ w2c, const float* __restrict__ b2c,
    float* __restrict__ o0, float* __restrict__ o1, float* __restrict__ o2)
{
    __shared__ float xs[CH][TH+2][TW+2];
    const int bid = blockIdx.x;
    const int wt = bid & 1;          // WPIX/TW = 2
    const int ht = (bid >> 1) & 31;  // HPIX/TH = 32
    const int n  = bid >> 6;         // image
    const int h0 = ht*TH, w0 = wt*TW;
    const int tid = threadIdx.x;

    const int PATCH = CH*(TH+2)*(TW+2);   // 16*6*66 = 6336
    for (int i = tid; i < PATCH; i += 256) {
        int cc = i % (TW+2);
        int r  = (i/(TW+2)) % (TH+2);
        int ic = i / ((TW+2)*(TH+2));
        int gh = h0 + r - 1, gw = w0 + cc - 1;
        float val = 0.f;
        if ((unsigned)gh < (unsigned)HPIX && (unsigned)gw < (unsigned)WPIX)
            val = xin[((n*CH + ic)*HPIX + gh)*WPIX + gw];
        xs[ic][r][cc] = val;
    }
    __syncthreads();

    const int tx = tid & 63, ty = tid >> 6;
    float a0[16], a1[16], a2[16];
    #pragma unroll
    for (int oc = 0; oc < 16; ++oc) {
        a0[oc] = b0c[oc];
        if constexpr (NC > 1) { a1[oc] = b1c[oc]; a2[oc] = b2c[oc]; }
    }

    for (int ic = 0; ic < 16; ++ic) {
        float xv[9];
        #pragma unroll
        for (int r = 0; r < 3; ++r)
            #pragma unroll
            for (int c = 0; c < 3; ++c)
                xv[r*3+c] = xs[ic][ty+r][tx+c];
        #pragma unroll
        for (int oc = 0; oc < 16; ++oc) {
            const int wb = (oc*16 + ic)*9;   // uniform -> scalar loads
            #pragma unroll
            for (int j = 0; j < 9; ++j) {
                a0[oc] = fmaf(xv[j], w0c[wb+j], a0[oc]);
                if constexpr (NC > 1) {
                    a1[oc] = fmaf(xv[j], w1c[wb+j], a1[oc]);
                    a2[oc] = fmaf(xv[j], w2c[wb+j], a2[oc]);
                }
            }
        }
    }

    const int h = h0 + ty, w = w0 + tx;
    #pragma unroll
    for (int oc = 0; oc < 16; ++oc) {
        int idx = ((n*CH + oc)*HPIX + h)*WPIX + w;
        o0[idx] = a0[oc];
        if constexpr (NC > 1) { o1[idx] = a1[oc]; o2[idx] = a2[oc]; }
    }
}

// ---------------- QK^T partial sums over d-slices --------------------------------------
// grid = 16 bh * NSLICE; each block: 64x64 scores partial over 512 pix * 2 ch.
__global__ __launch_bounds__(256) void qk_partial_k(
    const float* __restrict__ q, const float* __restrict__ k,
    float* __restrict__ partial)
{
    __shared__ float qs[64][65];
    __shared__ float ks[64][65];
    const int slice = blockIdx.x & (NSLICE-1);
    const int bh = blockIdx.x >> 5;
    const int b = bh >> 3, h = bh & 7;
    const int tid = threadIdx.x;
    const int ss = (tid & 15) * 4;
    const int tt = (tid >> 4) * 4;

    float acc[4][4];
    #pragma unroll
    for (int i = 0; i < 4; ++i)
        #pragma unroll
        for (int j = 0; j < 4; ++j) acc[i][j] = 0.f;

    for (int c = 0; c < 2; ++c) {
        for (int pc = 0; pc < 8; ++pc) {       // 8 chunks of 64 pix -> 512 pix/slice
            const int pixbase = slice*512 + pc*64;
            __syncthreads();
            for (int i = tid; i < 4096; i += 256) {
                int t = i >> 6, p = i & 63;
                int gidx = ((b*TT + t)*CH + 2*h + c)*HW + pixbase + p;
                qs[t][p] = q[gidx];
                ks[t][p] = k[gidx];
            }
            __syncthreads();
            for (int p = 0; p < 64; ++p) {
                float q4[4], k4[4];
                #pragma unroll
                for (int i = 0; i < 4; ++i) { q4[i] = qs[tt+i][p]; k4[i] = ks[ss+i][p]; }
                #pragma unroll
                for (int i = 0; i < 4; ++i)
                    #pragma unroll
                    for (int j = 0; j < 4; ++j)
                        acc[i][j] = fmaf(q4[i], k4[j], acc[i][j]);
            }
        }
    }

    float* pp = partial + (size_t)blockIdx.x * 4096;   // [bh][slice][t][s]
    #pragma unroll
    for (int i = 0; i < 4; ++i)
        #pragma unroll
        for (int j = 0; j < 4; ++j)
            pp[(tt+i)*64 + (ss+j)] = acc[i][j];
}

// ---------------- reduce partials -> logits --------------------------------------------
__global__ __launch_bounds__(256) void reduce_logits_k(
    const float* __restrict__ partial, float* __restrict__ logits)
{
    int idx = blockIdx.x * 256 + threadIdx.x;   // [0, 16*4096)
    int bh = idx >> 12, ts = idx & 4095;
    float s = 0.f;
    for (int sl = 0; sl < NSLICE; ++sl)
        s += partial[((size_t)(bh*NSLICE) + sl)*4096 + ts];
    logits[idx] = s;
}

// ---------------- causal softmax; writes att TRANSPOSED: att[bh][s][t] -----------------
__global__ __launch_bounds__(256) void softmax_k(
    const float* __restrict__ logits, float* __restrict__ att)
{
    const int bh = blockIdx.x;
    const int tid = threadIdx.x;
    const int t = tid >> 2, sg = tid & 3;       // 4 lanes cooperate on one row t
    float r[16];
    #pragma unroll
    for (int i = 0; i < 16; ++i) {
        int s = sg*16 + i;
        float val = logits[bh*4096 + t*64 + s] * SCALE_ATT;
        r[i] = (s <= t) ? val : -1e30f;
    }
    float m = r[0];
    #pragma unroll
    for (int i = 1; i < 16; ++i) m = fmaxf(m, r[i]);
    m = fmaxf(m, __shfl_xor(m, 1));
    m = fmaxf(m, __shfl_xor(m, 2));
    float sum = 0.f;
    #pragma unroll
    for (int i = 0; i < 16; ++i) {
        int s = sg*16 + i;
        r[i] = (s <= t) ? expf(r[i] - m) : 0.f;
        sum += r[i];
    }
    sum += __shfl_xor(sum, 1);
    sum += __shfl_xor(sum, 2);
    const float inv = 1.f / sum;
    #pragma unroll
    for (int i = 0; i < 16; ++i) {
        int s = sg*16 + i;
        att[(bh*64 + s)*64 + t] = r[i] * inv;   // transposed for uniform reads in attv
    }
}

// ---------------- y = att @ v, written directly in conv layout [n][oc][pix] ------------
// grid = 16 bh * 128 chunks; thread owns one d (c,pix), accumulates all 64 t.
__global__ __launch_bounds__(256) void attv_k(
    const float* __restrict__ v, const float* __restrict__ att,
    float* __restrict__ y)
{
    const int chunk = blockIdx.x & 127;
    const int bh = blockIdx.x >> 7;
    const int b = bh >> 3, h = bh & 7;
    const int d = chunk*256 + threadIdx.x;      // [0, 32768)
    const int c = d >> 14, pix = d & (HW-1);
    const float* vp = v + ((size_t)(b*TT)*CH + 2*h + c)*HW + pix;
    const float* ap = att + bh*4096;            // attT[s][t]
    float acc[64];
    #pragma unroll
    for (int t = 0; t < 64; ++t) acc[t] = 0.f;
    for (int s = 0; s < 64; ++s) {
        float vv = vp[(size_t)s*CH*HW];
        #pragma unroll
        for (int t = 0; t < 64; ++t)
            acc[t] = fmaf(ap[s*64 + t], vv, acc[t]);   // uniform -> scalar loads
    }
    float* yp = y + ((size_t)(b*TT)*CH + 2*h + c)*HW + pix;
    #pragma unroll
    for (int t = 0; t < 64; ++t)
        yp[(size_t)t*CH*HW] = acc[t];
}

// ---------------- launch ---------------------------------------------------------------
extern "C" void kernel_launch(void* const* d_in, const int* in_sizes, int n_in,
                              void* d_out, int out_size, void* d_ws, size_t ws_size,
                              hipStream_t stream)
{
    const float* x  = (const float*)d_in[0];
    const float* wq = (const float*)d_in[1];
    const float* bq = (const float*)d_in[2];
    const float* wk = (const float*)d_in[3];
    const float* bk = (const float*)d_in[4];
    const float* wv = (const float*)d_in[5];
    const float* bv = (const float*)d_in[6];
    const float* wo = (const float*)d_in[7];
    const float* bo = (const float*)d_in[8];
    float* out = (float*)d_out;

    float* ws = (float*)d_ws;
    float* q = ws;
    float* k = ws + QSZ;
    float* v = ws + 2*(size_t)QSZ;
    float* partial = ws + 3*(size_t)QSZ;            // 16*32*4096 = 2,097,152 floats
    float* logits  = partial + 16*NSLICE*4096;      // 65,536 floats
    float* att     = logits + 65536;                // 65,536 floats
    float* y = q;                                   // q is dead after softmax

    conv3x3_k<3><<<8192, 256, 0, stream>>>(x, wq, bq, wk, bk, wv, bv, q, k, v);
    qk_partial_k<<<16*NSLICE, 256, 0, stream>>>(q, k, partial);
    reduce_logits_k<<<256, 256, 0, stream>>>(partial, logits);
    softmax_k<<<16, 256, 0, stream>>>(logits, att);
    attv_k<<<16*128, 256, 0, stream>>>(v, att, y);
    conv3x3_k<1><<<8192, 256, 0, stream>>>(y, wo, bo, nullptr, nullptr, nullptr, nullptr,
                                           out, nullptr, nullptr);
}